// Round 4
// 338.258 us; speedup vs baseline: 1.0019x; 1.0019x over previous
//
#include <hip/hip_runtime.h>

#define NE 32
#define NT 2048
#define NH 1024
#define NI 512
#define NK 4
#define CAP 512

typedef __attribute__((ext_vector_type(8))) short short8;
typedef __attribute__((ext_vector_type(4))) float floatx4;

// ---- fp32 -> bf16 (RNE) pair pack -> one dword ----
static __device__ __forceinline__ unsigned pk_bf16(float x, float y) {
#if __has_builtin(__builtin_amdgcn_cvt_pk_bf16_f32)
    typedef __attribute__((ext_vector_type(2))) __bf16 bf16x2;
    union { bf16x2 v; unsigned u; } c;
    c.v = __builtin_amdgcn_cvt_pk_bf16_f32(x, y);
    return c.u;
#else
    union { float f; unsigned u; } a, b;
    a.f = x; b.f = y;
    unsigned ua = (a.u + 0x7fffu + ((a.u >> 16) & 1u)) >> 16;
    unsigned ub = (b.u + 0x7fffu + ((b.u >> 16) & 1u)) >> 16;
    return (ua & 0xffffu) | (ub << 16);
#endif
}

static __device__ __forceinline__ short8 pack8(const float* p) {
    union { unsigned u[4]; short8 s; } c;
    c.u[0] = pk_bf16(p[0], p[1]);
    c.u[1] = pk_bf16(p[2], p[3]);
    c.u[2] = pk_bf16(p[4], p[5]);
    c.u[3] = pk_bf16(p[6], p[7]);
    return c.s;
}

static __device__ __forceinline__ unsigned short bf16_1(float x) {
    return (unsigned short)(pk_bf16(x, 0.f) & 0xffffu);
}

// ---------------- routing ----------------
__global__ void route_kernel(const int* __restrict__ idx,
                             const float* __restrict__ w,
                             int* __restrict__ counts,
                             int* __restrict__ tok,
                             float* __restrict__ wgt) {
    int tid = blockIdx.x * blockDim.x + threadIdx.x;
    if (tid >= NT * NK) return;
    int e = idx[tid];
    int pos = atomicAdd(&counts[e], 1);
    if (pos < CAP) {
        tok[e * CAP + pos] = tid;          // tid = t*NK + k
        wgt[e * CAP + pos] = w[tid];
    }
}

// ---------------- hidden fp32 -> bf16 ----------------
__global__ void cvt_hidden(const float* __restrict__ hidden,
                           unsigned short* __restrict__ hb16) {
    size_t i = (size_t)(blockIdx.x * 256 + threadIdx.x) * 8;
    float tmp[8];
    *(floatx4*)tmp       = *(const floatx4*)(hidden + i);
    *(floatx4*)(tmp + 4) = *(const floatx4*)(hidden + i + 4);
    *(short8*)(hb16 + i) = pack8(tmp);
}

// ---------------- gate/up MFMA GEMM + SiLU ----------------
// tile: 128 entries x 32 j (gate AND up => 64 B-rows), BK=64
// 2-tile unrolled body: A prefetch distance 1, B (fp32 weights) distance 2
__global__ __launch_bounds__(256, 4) void gateup_mfma(
    const unsigned short* __restrict__ hb16,   // [NT][NH] bf16
    const float* __restrict__ gup,             // [NE][2*NI][NH] fp32
    const int* __restrict__ counts,
    const int* __restrict__ tok,
    unsigned short* __restrict__ hbuf)         // [NT*NK][NI] bf16
{
    int e = blockIdx.z;
    int cnt = counts[e];
    int m0 = blockIdx.y * 128;
    if (m0 >= cnt) return;
    int j0 = blockIdx.x * 32;

    __shared__ __align__(16) char smem[27648];   // As[128][72] | Bs[64][72] ; epilogue: upb[2][64][36] f32
    __shared__ int tks[128];

    short (*As)[72] = (short(*)[72])smem;
    short (*Bs)[72] = (short(*)[72])(smem + 18432);
    float (*upb)[64][36] = (float(*)[64][36])smem;

    int tid = threadIdx.x;
    if (tid < 128) {
        int mi = m0 + tid;
        tks[tid] = tok[e * CAP + (mi < cnt ? mi : m0)];
    }
    __syncthreads();

    // A: 8 lanes per row (16B each), 32 rows per pass, 4 passes
    int arow_base = tid >> 3;            // 0..31
    int acol = (tid & 7) * 8;            // bf16 col
    const unsigned short* ap[4];
#pragma unroll
    for (int p = 0; p < 4; p++)
        ap[p] = hb16 + (size_t)(tks[p * 32 + arow_base] >> 2) * NH + acol;

    // B: 16 lanes per row (float4 each), 16 rows per pass, 4 passes
    // pass 0..1: gate rows j0..j0+31 ; pass 2..3: up rows NI+j0..NI+j0+31
    int brow_base = tid >> 4;            // 0..15
    int bcol = (tid & 15) * 4;           // float col
    const float* bp0 = gup + (size_t)e * (2 * NI) * NH
                           + (size_t)(j0 + brow_base) * NH + bcol;
#define GUP_OFF(p) ((size_t)(p) * 16 * NH + ((p) >= 2 ? (size_t)(NI - 32) * NH : (size_t)0))

    int wave = tid >> 6, lane = tid & 63;
    int wm = wave >> 1;          // row half
    int wv = wave & 1;           // 0: gate, 1: up
    int lcol = lane & 15;
    int quad = lane >> 4;
    int lk = quad * 8;

    floatx4 acc[4][2];
#pragma unroll
    for (int a = 0; a < 4; a++)
#pragma unroll
        for (int b = 0; b < 2; b++) acc[a][b] = (floatx4){0.f, 0.f, 0.f, 0.f};

    short8 ra[4];
    float4 rbA[4], rbB[4];
#pragma unroll
    for (int p = 0; p < 4; p++) ra[p] = *(const short8*)(ap[p]);
#pragma unroll
    for (int p = 0; p < 4; p++) rbA[p] = *(const float4*)(bp0 + GUP_OFF(p));
#pragma unroll
    for (int p = 0; p < 4; p++) rbB[p] = *(const float4*)(bp0 + GUP_OFF(p) + 64);

    auto commit = [&](short8* raq, float4* rbq) {
#pragma unroll
        for (int p = 0; p < 4; p++)
            *(short8*)&As[p * 32 + arow_base][acol] = raq[p];
#pragma unroll
        for (int p = 0; p < 4; p++) {
            uint2 u;
            u.x = pk_bf16(rbq[p].x, rbq[p].y);
            u.y = pk_bf16(rbq[p].z, rbq[p].w);
            *(uint2*)&Bs[p * 16 + brow_base][bcol] = u;
        }
    };
    auto mfma_step = [&]() {
#pragma unroll
        for (int ks = 0; ks < 2; ks++) {
            short8 af[4], bfr[2];
#pragma unroll
            for (int mt = 0; mt < 4; mt++)
                af[mt] = *(const short8*)&As[wm * 64 + mt * 16 + lcol][ks * 32 + lk];
#pragma unroll
            for (int nt = 0; nt < 2; nt++)
                bfr[nt] = *(const short8*)&Bs[wv * 32 + nt * 16 + lcol][ks * 32 + lk];
#pragma unroll
            for (int mt = 0; mt < 4; mt++)
#pragma unroll
                for (int nt = 0; nt < 2; nt++)
                    acc[mt][nt] = __builtin_amdgcn_mfma_f32_16x16x32_bf16(
                        af[mt], bfr[nt], acc[mt][nt], 0, 0, 0);
        }
    };

    for (int h0 = 0; h0 < NH; h0 += 128) {
        // ---- phase 0: K-tile h0 (A from dist-1, B from rbA loaded 2 tiles ago) ----
        commit(ra, rbA);
        __syncthreads();
        {
            int ha = h0 + 64;                    // always < NH
#pragma unroll
            for (int p = 0; p < 4; p++) ra[p] = *(const short8*)(ap[p] + ha);
            int hb = h0 + 128;
            if (hb < NH) {
#pragma unroll
                for (int p = 0; p < 4; p++) rbA[p] = *(const float4*)(bp0 + GUP_OFF(p) + hb);
            }
        }
        mfma_step();
        __syncthreads();

        // ---- phase 1: K-tile h0+64 ----
        commit(ra, rbB);
        __syncthreads();
        {
            int ha = h0 + 128;
            if (ha < NH) {
#pragma unroll
                for (int p = 0; p < 4; p++) ra[p] = *(const short8*)(ap[p] + ha);
#pragma unroll
                for (int p = 0; p < 4; p++) rbB[p] = *(const float4*)(bp0 + GUP_OFF(p) + ha + 64);
            }
        }
        mfma_step();
        __syncthreads();
    }

    // epilogue: up waves park acc in LDS; gate waves fuse SiLU and store bf16
    if (wv == 1) {
#pragma unroll
        for (int mt = 0; mt < 4; mt++)
#pragma unroll
            for (int nt = 0; nt < 2; nt++)
#pragma unroll
                for (int i = 0; i < 4; i++)
                    upb[wm][mt * 16 + quad * 4 + i][nt * 16 + lcol] = acc[mt][nt][i];
    }
    __syncthreads();
    if (wv == 0) {
#pragma unroll
        for (int mt = 0; mt < 4; mt++) {
#pragma unroll
            for (int i = 0; i < 4; i++) {
                int lm = mt * 16 + quad * 4 + i;
                int m = wm * 64 + lm;
                if (m0 + m < cnt) {
                    unsigned short* hp = hbuf + (size_t)tks[m] * NI + j0;
#pragma unroll
                    for (int nt = 0; nt < 2; nt++) {
                        float g = acc[mt][nt][i];
                        float u = upb[wm][lm][nt * 16 + lcol];
                        float h = g / (1.f + __expf(-g)) * u;
                        hp[nt * 16 + lcol] = bf16_1(h);
                    }
                }
            }
        }
    }
}

// ---------------- down MFMA GEMM + weight-scale ----------------
// tile: 128 entries x 64 H-cols, BK=64 over NI, 2-tile unrolled body (A d1 / B d2)
// ATOMIC=false: plain weighted stores into pairbuf[NT*NK][NH] (no atomics)
template<bool ATOMIC>
__global__ __launch_bounds__(256, 4) void down_mfma(
    const unsigned short* __restrict__ hbuf,   // [NT*NK][NI] bf16
    const float* __restrict__ dwn,             // [NE][NH][NI] fp32
    const int* __restrict__ counts,
    const int* __restrict__ tok,
    const float* __restrict__ wgt,
    float* __restrict__ outp)                  // ATOMIC: out[NT][NH] ; else pairbuf[NT*NK][NH]
{
    int e = blockIdx.z;
    int cnt = counts[e];
    int m0 = blockIdx.y * 128;
    if (m0 >= cnt) return;
    int n0 = blockIdx.x * 64;

    __shared__ __align__(16) short As[128][72];
    __shared__ __align__(16) short Bs[64][72];
    __shared__ int tks[128];
    __shared__ float wls[128];

    int tid = threadIdx.x;
    if (tid < 128) {
        int mi = m0 + tid;
        int src = e * CAP + (mi < cnt ? mi : m0);
        tks[tid] = tok[src];
        wls[tid] = wgt[src];
    }
    __syncthreads();

    int arow_base = tid >> 3;
    int acol = (tid & 7) * 8;
    const unsigned short* ap[4];
#pragma unroll
    for (int p = 0; p < 4; p++)
        ap[p] = hbuf + (size_t)tks[p * 32 + arow_base] * NI + acol;

    int brow_base = tid >> 4;
    int bcol = (tid & 15) * 4;
    const float* bp0 = dwn + (size_t)e * NH * NI + (size_t)(n0 + brow_base) * NI + bcol;
#define DN_OFF(p) ((size_t)(p) * 16 * NI)

    int wave = tid >> 6, lane = tid & 63;
    int wm = wave >> 1, wn = wave & 1;
    int lcol = lane & 15;
    int quad = lane >> 4;
    int lk = quad * 8;

    floatx4 acc[4][2];
#pragma unroll
    for (int a = 0; a < 4; a++)
#pragma unroll
        for (int b = 0; b < 2; b++) acc[a][b] = (floatx4){0.f, 0.f, 0.f, 0.f};

    short8 ra[4];
    float4 rbA[4], rbB[4];
#pragma unroll
    for (int p = 0; p < 4; p++) ra[p] = *(const short8*)(ap[p]);
#pragma unroll
    for (int p = 0; p < 4; p++) rbA[p] = *(const float4*)(bp0 + DN_OFF(p));
#pragma unroll
    for (int p = 0; p < 4; p++) rbB[p] = *(const float4*)(bp0 + DN_OFF(p) + 64);

    auto commit = [&](short8* raq, float4* rbq) {
#pragma unroll
        for (int p = 0; p < 4; p++)
            *(short8*)&As[p * 32 + arow_base][acol] = raq[p];
#pragma unroll
        for (int p = 0; p < 4; p++) {
            uint2 u;
            u.x = pk_bf16(rbq[p].x, rbq[p].y);
            u.y = pk_bf16(rbq[p].z, rbq[p].w);
            *(uint2*)&Bs[p * 16 + brow_base][bcol] = u;
        }
    };
    auto mfma_step = [&]() {
#pragma unroll
        for (int ks = 0; ks < 2; ks++) {
            short8 af[4], bfr[2];
#pragma unroll
            for (int mt = 0; mt < 4; mt++)
                af[mt] = *(const short8*)&As[wm * 64 + mt * 16 + lcol][ks * 32 + lk];
#pragma unroll
            for (int nt = 0; nt < 2; nt++)
                bfr[nt] = *(const short8*)&Bs[wn * 32 + nt * 16 + lcol][ks * 32 + lk];
#pragma unroll
            for (int mt = 0; mt < 4; mt++)
#pragma unroll
                for (int nt = 0; nt < 2; nt++)
                    acc[mt][nt] = __builtin_amdgcn_mfma_f32_16x16x32_bf16(
                        af[mt], bfr[nt], acc[mt][nt], 0, 0, 0);
        }
    };

    for (int i0 = 0; i0 < NI; i0 += 128) {
        commit(ra, rbA);
        __syncthreads();
        {
            int ia = i0 + 64;                    // always < NI
#pragma unroll
            for (int p = 0; p < 4; p++) ra[p] = *(const short8*)(ap[p] + ia);
            int ib = i0 + 128;
            if (ib < NI) {
#pragma unroll
                for (int p = 0; p < 4; p++) rbA[p] = *(const float4*)(bp0 + DN_OFF(p) + ib);
            }
        }
        mfma_step();
        __syncthreads();

        commit(ra, rbB);
        __syncthreads();
        {
            int ia = i0 + 128;
            if (ia < NI) {
#pragma unroll
                for (int p = 0; p < 4; p++) ra[p] = *(const short8*)(ap[p] + ia);
#pragma unroll
                for (int p = 0; p < 4; p++) rbB[p] = *(const float4*)(bp0 + DN_OFF(p) + ia + 64);
            }
        }
        mfma_step();
        __syncthreads();
    }

#pragma unroll
    for (int mt = 0; mt < 4; mt++)
#pragma unroll
        for (int i = 0; i < 4; i++) {
            int m = wm * 64 + mt * 16 + quad * 4 + i;
            if (m0 + m < cnt) {
                float wl = wls[m];
                if (ATOMIC) {
                    float* op = outp + (size_t)(tks[m] >> 2) * NH + n0 + wn * 32;
#pragma unroll
                    for (int nt = 0; nt < 2; nt++)
                        atomicAdd(op + nt * 16 + lcol, acc[mt][nt][i] * wl);
                } else {
                    float* op = outp + (size_t)tks[m] * NH + n0 + wn * 32;
#pragma unroll
                    for (int nt = 0; nt < 2; nt++)
                        op[nt * 16 + lcol] = acc[mt][nt][i] * wl;
                }
            }
        }
}

// ---------------- per-token reduction over the K=4 pair rows ----------------
__global__ void reduce_pairs(const float* __restrict__ pairbuf,
                             float* __restrict__ out) {
    int i = blockIdx.x * 256 + threadIdx.x;      // over NT*NH/4
    int t = i / (NH / 4);
    int c = (i - t * (NH / 4)) * 4;
    const float* p = pairbuf + (size_t)t * NK * NH + c;
    floatx4 a = *(const floatx4*)p;
    a += *(const floatx4*)(p + NH);
    a += *(const floatx4*)(p + 2 * NH);
    a += *(const floatx4*)(p + 3 * NH);
    *(floatx4*)(out + (size_t)t * NH + c) = a;
}

extern "C" void kernel_launch(void* const* d_in, const int* in_sizes, int n_in,
                              void* d_out, int out_size, void* d_ws, size_t ws_size,
                              hipStream_t stream) {
    const float* hidden = (const float*)d_in[0];
    const int*   tk_idx = (const int*)d_in[1];
    const float* tk_w   = (const float*)d_in[2];
    const float* gup    = (const float*)d_in[3];
    const float* dwn    = (const float*)d_in[4];
    float* out = (float*)d_out;

    char* ws = (char*)d_ws;
    int*            counts = (int*)ws;                                            // 256 B
    int*            tok    = (int*)(ws + 256);                                    // 64 KB
    float*          wgt    = (float*)(ws + 256 + NE * CAP * 4);                   // 64 KB
    unsigned short* hb16   = (unsigned short*)(ws + 256 + 2 * NE * CAP * 4);      // 4 MB
    unsigned short* hbuf   = (unsigned short*)(ws + 256 + 2 * NE * CAP * 4
                                               + (size_t)NT * NH * 2);            // 8 MB
    float*          pairbuf = (float*)(ws + 256 + 2 * NE * CAP * 4
                                       + (size_t)NT * NH * 2
                                       + (size_t)NT * NK * NI * 2);               // 32 MB

    size_t need = 256 + 2 * (size_t)NE * CAP * 4 + (size_t)NT * NH * 2
                + (size_t)NT * NK * NI * 2 + (size_t)NT * NK * NH * 4;
    bool pair_ok = ws_size >= need;

    hipMemsetAsync(counts, 0, 256, stream);

    route_kernel<<<(NT * NK + 255) / 256, 256, 0, stream>>>(tk_idx, tk_w, counts, tok, wgt);
    cvt_hidden<<<(NT * NH / 8) / 256, 256, 0, stream>>>(hidden, hb16);

    dim3 gridG(NI / 32, CAP / 128, NE);    // (16, 4, 32)
    gateup_mfma<<<gridG, 256, 0, stream>>>(hb16, gup, counts, tok, hbuf);

    dim3 gridD(NH / 64, CAP / 128, NE);    // (16, 4, 32)
    if (pair_ok) {
        down_mfma<false><<<gridD, 256, 0, stream>>>(hbuf, dwn, counts, tok, wgt, pairbuf);
        reduce_pairs<<<(NT * NH / 4) / 256, 256, 0, stream>>>(pairbuf, out);
    } else {
        hipMemsetAsync(out, 0, (size_t)NT * NH * sizeof(float), stream);
        down_mfma<true><<<gridD, 256, 0, stream>>>(hbuf, dwn, counts, tok, wgt, out);
    }
}